// Round 1
// baseline (509.018 us; speedup 1.0000x reference)
//
#include <hip/hip_runtime.h>

// ESN fused kernel: input projection GEMM + leaky-tanh diagonal scan, chunked over L.
// B=32, D_IN=64, D_STATE=1024, L=2048, LEAK=0.5
#define B_  32
#define H_  64      // D_IN
#define P_  1024    // D_STATE
#define L_  2048
#define TL  64      // L-chunk per iteration
#define PB  64      // p's per block
#define US  68      // u_tile row stride (pad 64->68 floats, keeps 16B align, breaks bank aliasing)
#define TS  68      // proj/out tile row stride

__device__ __forceinline__ float tanh_fast(float x) {
    // tanh(x) = 1 - 2/(exp(2x)+1); exact saturation at +/-inf, no NaN.
    float e = __expf(2.0f * x);
    return 1.0f - 2.0f / (e + 1.0f);
}

__global__ __launch_bounds__(256, 2)
void esn_fused(const float* __restrict__ u, const float* __restrict__ w_in,
               const float* __restrict__ w_hh, const float* __restrict__ bias,
               float* __restrict__ out) {
    __shared__ float wT[H_ * PB];   // [h][p]   16 KB, staged once
    __shared__ float uT[H_ * US];   // [h][l]   17 KB
    __shared__ float pT[TL * TS];   // [l][p]   17 KB (proj, then x, in place)

    const int t  = threadIdx.x;
    const int b  = blockIdx.x >> 4;          // 32 b's
    const int p0 = (blockIdx.x & 15) * PB;   // 16 p-chunks

    // ---- stage w_in^T for this block's 64 p's (once) ----
    if (t < PB) {
        const float4* wrow = (const float4*)(w_in + (size_t)(p0 + t) * H_);
        #pragma unroll
        for (int hv = 0; hv < H_ / 4; ++hv) {
            float4 w4 = wrow[hv];
            wT[(hv * 4 + 0) * PB + t] = w4.x;
            wT[(hv * 4 + 1) * PB + t] = w4.y;
            wT[(hv * 4 + 2) * PB + t] = w4.z;
            wT[(hv * 4 + 3) * PB + t] = w4.w;
        }
    }
    // scan state (wave 0 threads own one p each)
    float x = 0.0f, dg = 0.0f, bs = 0.0f;
    if (t < PB) {
        dg = w_hh[(size_t)(p0 + t) * (P_ + 1)];  // diagonal of w_hh
        bs = bias[p0 + t];
    }
    __syncthreads();

    const int tx = t & 15;        // l-group: l = 4*tx .. 4*tx+3
    const int ty = t >> 4;        // p-group: p = 4*ty .. 4*ty+3 (ty 0..15)
    const int hs = t >> 2;        // staging/writeout row (0..63)
    const int cs = t & 3;         // staging/writeout 16-col group
    const float* ubase = u + (size_t)b * (H_ * L_) + (size_t)hs * L_;
    float* obase = out + (size_t)b * (P_ * L_) + (size_t)(p0 + hs) * L_;

    for (int lc = 0; lc < L_ / TL; ++lc) {
        const int l0 = lc * TL;

        // ---- stage u[b, :, l0:l0+64] -> uT[h][l] (coalesced float4) ----
        #pragma unroll
        for (int j = 0; j < 4; ++j) {
            const int col = cs * 16 + j * 4;
            float4 v = *(const float4*)(ubase + l0 + col);
            *(float4*)&uT[hs * US + col] = v;
        }
        __syncthreads();

        // ---- 64x64 GEMM: proj[l][p] = sum_h wT[h][p] * uT[h][l] ----
        float acc[4][4] = {};
        #pragma unroll 8
        for (int h = 0; h < H_; ++h) {
            float4 wv = *(const float4*)&wT[h * PB + ty * 4];
            float4 uv = *(const float4*)&uT[h * US + tx * 4];
            const float wr[4] = {wv.x, wv.y, wv.z, wv.w};
            const float ur[4] = {uv.x, uv.y, uv.z, uv.w};
            #pragma unroll
            for (int i = 0; i < 4; ++i)
                #pragma unroll
                for (int j = 0; j < 4; ++j)
                    acc[i][j] += wr[i] * ur[j];
        }
        // store transposed: pT[l][p]  (per-instruction 2-way banks max)
        #pragma unroll
        for (int j = 0; j < 4; ++j) {
            float4 o = make_float4(acc[0][j], acc[1][j], acc[2][j], acc[3][j]);
            *(float4*)&pT[(4 * tx + j) * TS + 4 * ty] = o;
        }
        __syncthreads();

        // ---- scan: wave 0, one p per lane; batch reads 8 deep to hide LDS latency ----
        if (t < PB) {
            #pragma unroll
            for (int g = 0; g < TL / 8; ++g) {
                float v[8];
                #pragma unroll
                for (int k = 0; k < 8; ++k) v[k] = pT[(g * 8 + k) * TS + t];
                #pragma unroll
                for (int k = 0; k < 8; ++k) {
                    float pre = v[k] + x * dg + bs;
                    x = 0.5f * x + 0.5f * tanh_fast(pre);
                    pT[(g * 8 + k) * TS + t] = x;   // in place
                }
            }
        }
        __syncthreads();

        // ---- write out[b, p, l0:l0+64] (float4, 16 contiguous l per thread) ----
        #pragma unroll
        for (int j = 0; j < 4; ++j) {
            const int lb = cs * 16 + j * 4;
            float4 o;
            o.x = pT[(lb + 0) * TS + hs];
            o.y = pT[(lb + 1) * TS + hs];
            o.z = pT[(lb + 2) * TS + hs];
            o.w = pT[(lb + 3) * TS + hs];
            *(float4*)(obase + l0 + lb) = o;
        }
        __syncthreads();
    }
}

extern "C" void kernel_launch(void* const* d_in, const int* in_sizes, int n_in,
                              void* d_out, int out_size, void* d_ws, size_t ws_size,
                              hipStream_t stream) {
    const float* u    = (const float*)d_in[0];  // [B, H, L]
    const float* w_in = (const float*)d_in[1];  // [P, H]
    const float* w_hh = (const float*)d_in[2];  // [P, P] (diag used)
    const float* bias = (const float*)d_in[3];  // [P]
    float* out = (float*)d_out;                 // [B, P, L]

    dim3 grid(B_ * (P_ / PB));  // 512 blocks
    dim3 block(256);
    esn_fused<<<grid, block, 0, stream>>>(u, w_in, w_hh, bias, out);
}

// Round 2
// 446.214 us; speedup vs baseline: 1.1407x; 1.1407x over previous
//
#include <hip/hip_runtime.h>

// ESN fused v2: prefetched GEMM + overlapped scan/writeout, 2 barriers/chunk.
// B=32, D_IN=64, D_STATE=1024, L=2048, LEAK=0.5
#define B_  32
#define H_  64      // D_IN
#define P_  1024    // D_STATE
#define L_  2048
#define TL  64      // L per chunk
#define PB  64      // p per block
#define US  68      // uT row stride (floats)
#define TS  68      // pT row stride (floats)
#define NCH (L_ / TL)

__global__ __launch_bounds__(256, 2)
void esn_fused(const float* __restrict__ u, const float* __restrict__ w_in,
               const float* __restrict__ w_hh, const float* __restrict__ bias,
               float* __restrict__ out) {
    __shared__ float wT[H_ * PB];       // [h][p]  16 KB, staged once
    __shared__ float uT[H_ * US];       // [h][l]  17.4 KB
    __shared__ float pT[2][TL * TS];    // [l][p]  2x17.4 KB, double-buffered

    const int t = threadIdx.x;
    // XCD swizzle: all 16 p-chunks of a batch b land on one XCD (bid%8 heuristic).
    const int bid = blockIdx.x;
    const int s   = bid >> 3;                       // 0..63
    const int b   = ((s >> 4) << 3) | (bid & 7);    // 0..31
    const int p0  = (s & 15) * PB;

    // ---- stage wT[h][p] (all 256 threads; 4 float4 each) ----
    {
        const int p  = t & 63;
        const int h0 = t >> 6;   // 0..3
        #pragma unroll
        for (int r = 0; r < 4; ++r) {
            const int hv = h0 + 4 * r;               // 0..15
            float4 w4 = *(const float4*)(w_in + (size_t)(p0 + p) * H_ + 4 * hv);
            wT[(4 * hv + 0) * PB + p] = w4.x;
            wT[(4 * hv + 1) * PB + p] = w4.y;
            wT[(4 * hv + 2) * PB + p] = w4.z;
            wT[(4 * hv + 3) * PB + p] = w4.w;
        }
    }
    // scan state (threads 0..63 own one p each)
    float x = 0.0f, d2 = 0.0f, bs2 = 0.0f;
    if (t < PB) {
        d2  = 2.0f * w_hh[(size_t)(p0 + t) * (P_ + 1)];
        bs2 = 2.0f * bias[p0 + t];
    }

    // staging map: thread -> (h-row hs, 4-col group c); per j: 4 lanes cover 64B contiguous
    const int hs = t >> 2;      // 0..63
    const int c  = t & 3;       // 0..3
    const float* ubase = u + (size_t)b * (H_ * L_) + (size_t)hs * L_;

    // GEMM map: 4x4 per thread
    const int tx = t & 15;      // l-group
    const int ty = t >> 4;      // p-group (0..15)

    // ---- prologue: load chunk 0, write uT ----
    float4 pf[4];
    #pragma unroll
    for (int j = 0; j < 4; ++j)
        pf[j] = *(const float4*)(ubase + 16 * j + 4 * c);
    #pragma unroll
    for (int j = 0; j < 4; ++j)
        *(float4*)&uT[hs * US + 16 * j + 4 * c] = pf[j];
    __syncthreads();

    for (int k = 0; k < NCH; ++k) {
        const int kn = (k + 1 < NCH) ? k + 1 : k;
        const int buf = k & 1;

        // ---- issue prefetch of chunk kn (hides HBM latency under GEMM) ----
        #pragma unroll
        for (int j = 0; j < 4; ++j)
            pf[j] = *(const float4*)(ubase + kn * TL + 16 * j + 4 * c);

        // ---- GEMM: proj[l][p] for this chunk ----
        float acc[4][4] = {};   // [p-idx][l-idx]
        #pragma unroll 8
        for (int h = 0; h < H_; ++h) {
            float4 wv = *(const float4*)&wT[h * PB + ty * 4];
            float4 uv = *(const float4*)&uT[h * US + tx * 4];
            const float wr[4] = {wv.x, wv.y, wv.z, wv.w};
            const float ur[4] = {uv.x, uv.y, uv.z, uv.w};
            #pragma unroll
            for (int i = 0; i < 4; ++i)
                #pragma unroll
                for (int j = 0; j < 4; ++j)
                    acc[i][j] = fmaf(wr[i], ur[j], acc[i][j]);
        }
        // store transposed into pT[buf][l][p] (float4 along p; minimal 8-group pattern)
        #pragma unroll
        for (int j = 0; j < 4; ++j) {
            float4 o = make_float4(acc[0][j], acc[1][j], acc[2][j], acc[3][j]);
            *(float4*)&pT[buf][(4 * tx + j) * TS + 4 * ty] = o;
        }
        __syncthreads();   // A: acc stored; GEMM reads of uT done

        // ---- phase A->B: stage uT(k+1); wave0 scans; threads 64.. write out chunk k-1 ----
        #pragma unroll
        for (int j = 0; j < 4; ++j)
            *(float4*)&uT[hs * US + 16 * j + 4 * c] = pf[j];

        if (t < PB) {
            // scan 64 steps: x' = 0.5x + 0.5*tanh(u + x*d + b); tanh via exp(2*pre)
            float* pcol = &pT[buf][t];
            #pragma unroll
            for (int g = 0; g < TL / 8; ++g) {
                float v[8], sv[8];
                #pragma unroll
                for (int m = 0; m < 8; ++m) v[m] = pcol[(8 * g + m) * TS];
                #pragma unroll
                for (int m = 0; m < 8; ++m) sv[m] = fmaf(2.0f, v[m], bs2);
                #pragma unroll
                for (int m = 0; m < 8; ++m) {
                    float e   = __expf(fmaf(x, d2, sv[m]));            // exp(2*pre)
                    float tmp = fmaf(0.5f, x, 0.5f);                   // off critical path
                    x = tmp - __builtin_amdgcn_rcpf(e + 1.0f);         // 0.5x + 0.5tanh
                    pcol[(8 * g + m) * TS] = x;
                }
            }
        } else if (k > 0) {
            // write out chunk k-1 from pT[1-buf] (intact: scan k-1 finished it,
            // acc-store k went to pT[buf]); 192 threads, hidden under the scan.
            const int pbuf = 1 - buf;
            const int lq   = (k - 1) * TL;
            const int idx0 = t - 64;     // 0..191
            for (int i = idx0; i < (TL / 4) * PB / 4 * 4 / 4 * 4; i += 192) {
                // i in 0..1023: p = i&63, j = i>>6 selects l-quad
                const int p = i & 63;
                const int j = i >> 6;    // 0..15
                float4 o;
                o.x = pT[pbuf][(4 * j + 0) * TS + p];
                o.y = pT[pbuf][(4 * j + 1) * TS + p];
                o.z = pT[pbuf][(4 * j + 2) * TS + p];
                o.w = pT[pbuf][(4 * j + 3) * TS + p];
                *(float4*)(out + (size_t)b * (P_ * L_) + (size_t)(p0 + p) * L_ + lq + 4 * j) = o;
            }
        }
        __syncthreads();   // B: scan + uT stage + writeout(k-1) done
    }

    // ---- epilogue: write out last chunk (all 256 threads, conflict-free map) ----
    {
        const int buf = (NCH - 1) & 1;
        const int lq  = (NCH - 1) * TL;
        const int p   = t >> 2;   // 0..63
        const int cc  = t & 3;
        float* obase = out + (size_t)b * (P_ * L_) + (size_t)(p0 + p) * L_ + lq;
        #pragma unroll
        for (int kk = 0; kk < 4; ++kk) {
            const int lb = kk * 16 + cc * 4;
            float4 o;
            o.x = pT[buf][(lb + 0) * TS + p];
            o.y = pT[buf][(lb + 1) * TS + p];
            o.z = pT[buf][(lb + 2) * TS + p];
            o.w = pT[buf][(lb + 3) * TS + p];
            *(float4*)(obase + lb) = o;
        }
    }
}

extern "C" void kernel_launch(void* const* d_in, const int* in_sizes, int n_in,
                              void* d_out, int out_size, void* d_ws, size_t ws_size,
                              hipStream_t stream) {
    const float* u    = (const float*)d_in[0];  // [B, H, L]
    const float* w_in = (const float*)d_in[1];  // [P, H]
    const float* w_hh = (const float*)d_in[2];  // [P, P] (diag used)
    const float* bias = (const float*)d_in[3];  // [P]
    float* out = (float*)d_out;                 // [B, P, L]

    dim3 grid(B_ * (P_ / PB));  // 512 blocks
    dim3 block(256);
    esn_fused<<<grid, block, 0, stream>>>(u, w_in, w_hh, bias, out);
}

// Round 3
// 322.561 us; speedup vs baseline: 1.5781x; 1.3833x over previous
//
#include <hip/hip_runtime.h>
#include <stdint.h>

// ESN fused v3: split-bf16 MFMA GEMM + row-major pT (b128 scan/writeout).
// B=32, D_IN=64, D_STATE=1024, L=2048, LEAK=0.5
#define B_   32
#define H_   64
#define P_   1024
#define L_   2048
#define TL   64
#define PB   64
#define NCH  (L_ / TL)
#define UST  68   // uB row stride in u32 (row = 272 B, 16B-aligned, banks 4l+h)
#define PST  68   // pT row stride in f32

typedef __attribute__((ext_vector_type(8))) short short8;
typedef __attribute__((ext_vector_type(4))) float f32x4;
typedef __attribute__((ext_vector_type(4))) int   i32x4;

__device__ __forceinline__ short8 as_short8(i32x4 v) {
    union { i32x4 i; short8 s; } u; u.i = v; return u.s;
}

// f = hi(bf16, trunc) + lo(bf16, RNE of remainder); packed as hi | lo<<16
__device__ __forceinline__ unsigned pack_hilo(float f) {
    unsigned ub = __float_as_uint(f);
    float    fh = __uint_as_float(ub & 0xFFFF0000u);
    float    rm = f - fh;                       // exact
    unsigned r  = __float_as_uint(rm);
    r += 0x7FFFu + ((r >> 16) & 1u);            // RNE to bf16
    return (ub >> 16) | (r & 0xFFFF0000u);
}

__global__ __launch_bounds__(256, 2)
void esn_fused(const float* __restrict__ u, const float* __restrict__ w_in,
               const float* __restrict__ w_hh, const float* __restrict__ bias,
               float* __restrict__ out) {
    __shared__ unsigned uB[TL * UST];      // [l][h] packed hi/lo bf16   17.4 KB
    __shared__ float    pT[2][PB * PST];   // [p][l]                     34.8 KB

    const int t   = threadIdx.x;
    const int bid = blockIdx.x;
    const int s_  = bid >> 3;                       // XCD swizzle: same-b on one XCD
    const int b   = ((s_ >> 4) << 3) | (bid & 7);
    const int p0  = (s_ & 15) * PB;

    const int wv  = t >> 6;        // wave 0..3 -> p-strip wv*16
    const int ln  = t & 63;
    const int n16 = ln & 15;       // MFMA m/n index
    const int q   = ln >> 4;       // MFMA quad (k-group)

    // ---- A-fragments: w_in rows, split bf16 hi/lo, held in registers ----
    short8 a_hi[2], a_lo[2];
    {
        const float* wrow = w_in + (size_t)(p0 + wv * 16 + n16) * H_;
        #pragma unroll
        for (int s = 0; s < 2; ++s) {
            float v[8];
            *(float4*)&v[0] = *(const float4*)(wrow + s * 32 + q * 8);
            *(float4*)&v[4] = *(const float4*)(wrow + s * 32 + q * 8 + 4);
            #pragma unroll
            for (int j = 0; j < 8; ++j) {
                unsigned ub = __float_as_uint(v[j]);
                a_hi[s][j] = (short)(ub >> 16);
                float rm = v[j] - __uint_as_float(ub & 0xFFFF0000u);
                unsigned r = __float_as_uint(rm);
                r += 0x7FFFu + ((r >> 16) & 1u);
                a_lo[s][j] = (short)(r >> 16);
            }
        }
    }

    // scan state (wave 0, one p per lane)
    float x = 0.0f, d2 = 0.0f, bs2 = 0.0f;
    if (t < PB) {
        d2  = 2.0f * w_hh[(size_t)(p0 + t) * (P_ + 1)];
        bs2 = 2.0f * bias[p0 + t];
    }

    // staging maps (threads 64..255): jobA rows 16..63, jobB (t<128) rows 0..15
    const int  hA   = t >> 2;            // 16..63 for t>=64
    const int  cA   = t & 3;
    const bool jobB = (t >= 64 && t < 128);
    const int  hB   = (t - 64) >> 2;     // 0..15
    const float* ub_ = u + (size_t)b * (H_ * L_);

    float4 pfA[4], pfB[4];

    // ---- prologue: load + stage chunk 0 ----
    if (t >= 64) {
        #pragma unroll
        for (int j = 0; j < 4; ++j)
            pfA[j] = *(const float4*)(ub_ + (size_t)hA * L_ + 16 * j + 4 * cA);
        if (jobB)
            #pragma unroll
            for (int j = 0; j < 4; ++j)
                pfB[j] = *(const float4*)(ub_ + (size_t)hB * L_ + 16 * j + 4 * cA);
        #pragma unroll
        for (int j = 0; j < 4; ++j) {
            const int l = 16 * j + 4 * cA;
            uB[(l + 0) * UST + hA] = pack_hilo(pfA[j].x);
            uB[(l + 1) * UST + hA] = pack_hilo(pfA[j].y);
            uB[(l + 2) * UST + hA] = pack_hilo(pfA[j].z);
            uB[(l + 3) * UST + hA] = pack_hilo(pfA[j].w);
        }
        if (jobB)
            #pragma unroll
            for (int j = 0; j < 4; ++j) {
                const int l = 16 * j + 4 * cA;
                uB[(l + 0) * UST + hB] = pack_hilo(pfB[j].x);
                uB[(l + 1) * UST + hB] = pack_hilo(pfB[j].y);
                uB[(l + 2) * UST + hB] = pack_hilo(pfB[j].z);
                uB[(l + 3) * UST + hB] = pack_hilo(pfB[j].w);
            }
    }
    __syncthreads();

    for (int k = 0; k < NCH; ++k) {
        const int buf = k & 1;
        const int kn  = (k + 1 < NCH) ? k + 1 : k;

        // ---- prefetch next u chunk into registers (hides HBM under GEMM) ----
        if (t >= 64) {
            #pragma unroll
            for (int j = 0; j < 4; ++j)
                pfA[j] = *(const float4*)(ub_ + (size_t)hA * L_ + kn * TL + 16 * j + 4 * cA);
            if (jobB)
                #pragma unroll
                for (int j = 0; j < 4; ++j)
                    pfB[j] = *(const float4*)(ub_ + (size_t)hB * L_ + kn * TL + 16 * j + 4 * cA);
        }

        // ---- MFMA GEMM: 64p x 64l, K=64, split bf16 (3 products) ----
        #pragma unroll
        for (int jt = 0; jt < 4; ++jt) {
            f32x4 acc = {0.0f, 0.0f, 0.0f, 0.0f};
            #pragma unroll
            for (int s = 0; s < 2; ++s) {
                const unsigned* bp = &uB[(jt * 16 + n16) * UST + s * 32 + q * 8];
                i32x4 r0 = *(const i32x4*)bp;
                i32x4 r1 = *(const i32x4*)(bp + 4);
                i32x4 fh, fl;
                fh.x = __builtin_amdgcn_perm(r0.y, r0.x, 0x05040100u);
                fh.y = __builtin_amdgcn_perm(r0.w, r0.z, 0x05040100u);
                fh.z = __builtin_amdgcn_perm(r1.y, r1.x, 0x05040100u);
                fh.w = __builtin_amdgcn_perm(r1.w, r1.z, 0x05040100u);
                fl.x = __builtin_amdgcn_perm(r0.y, r0.x, 0x07060302u);
                fl.y = __builtin_amdgcn_perm(r0.w, r0.z, 0x07060302u);
                fl.z = __builtin_amdgcn_perm(r1.y, r1.x, 0x07060302u);
                fl.w = __builtin_amdgcn_perm(r1.w, r1.z, 0x07060302u);
                short8 bh = as_short8(fh), bl = as_short8(fl);
                acc = __builtin_amdgcn_mfma_f32_16x16x32_bf16(a_hi[s], bh, acc, 0, 0, 0);
                acc = __builtin_amdgcn_mfma_f32_16x16x32_bf16(a_hi[s], bl, acc, 0, 0, 0);
                acc = __builtin_amdgcn_mfma_f32_16x16x32_bf16(a_lo[s], bh, acc, 0, 0, 0);
            }
            // C/D: col(l) = lane&15, row(p) = quad*4 + r  -> scatter b32, 2-way max
            #pragma unroll
            for (int r = 0; r < 4; ++r)
                pT[buf][(wv * 16 + q * 4 + r) * PST + jt * 16 + n16] = acc[r];
        }
        __syncthreads();   // A: pT[buf] complete; uB reads done

        if (t < PB) {
            // ---- scan 64 steps in-place on own row (b128 in/out) ----
            float* row = &pT[buf][t * PST];
            #pragma unroll
            for (int g = 0; g < 8; ++g) {
                float4 va = *(float4*)(row + 8 * g);
                float4 vb = *(float4*)(row + 8 * g + 4);
                float v[8] = {va.x, va.y, va.z, va.w, vb.x, vb.y, vb.z, vb.w};
                float xs[8];
                #pragma unroll
                for (int m = 0; m < 8; ++m) {
                    float sv  = fmaf(2.0f, v[m], bs2);
                    float e   = __expf(fmaf(x, d2, sv));          // exp(2*pre)
                    float tmp = fmaf(0.5f, x, 0.5f);
                    x = tmp - __builtin_amdgcn_rcpf(e + 1.0f);    // 0.5x + 0.5tanh
                    xs[m] = x;
                }
                *(float4*)(row + 8 * g)     = make_float4(xs[0], xs[1], xs[2], xs[3]);
                *(float4*)(row + 8 * g + 4) = make_float4(xs[4], xs[5], xs[6], xs[7]);
            }
        } else {
            // ---- stage uB for chunk k+1 ----
            #pragma unroll
            for (int j = 0; j < 4; ++j) {
                const int l = 16 * j + 4 * cA;
                uB[(l + 0) * UST + hA] = pack_hilo(pfA[j].x);
                uB[(l + 1) * UST + hA] = pack_hilo(pfA[j].y);
                uB[(l + 2) * UST + hA] = pack_hilo(pfA[j].z);
                uB[(l + 3) * UST + hA] = pack_hilo(pfA[j].w);
            }
            if (jobB)
                #pragma unroll
                for (int j = 0; j < 4; ++j) {
                    const int l = 16 * j + 4 * cA;
                    uB[(l + 0) * UST + hB] = pack_hilo(pfB[j].x);
                    uB[(l + 1) * UST + hB] = pack_hilo(pfB[j].y);
                    uB[(l + 2) * UST + hB] = pack_hilo(pfB[j].z);
                    uB[(l + 3) * UST + hB] = pack_hilo(pfB[j].w);
                }
            // ---- write out chunk k-1: 16 lanes cover one 256B-contig p-row ----
            if (k > 0) {
                const float* pbase = pT[1 - buf];
                float* ob = out + (size_t)b * (P_ * L_) + (size_t)p0 * L_ + (size_t)(k - 1) * TL;
                for (int i = t - 64; i < 1024; i += 192) {
                    const int p = i >> 4, j = i & 15;
                    float4 o = *(const float4*)(pbase + p * PST + 4 * j);
                    *(float4*)(ob + (size_t)p * L_ + 4 * j) = o;
                }
            }
        }
        __syncthreads();   // B: scan + stage + writeout done
    }

    // ---- epilogue: write out last chunk (all 256 threads) ----
    {
        const int buf = (NCH - 1) & 1;
        const float* pbase = pT[buf];
        float* ob = out + (size_t)b * (P_ * L_) + (size_t)p0 * L_ + (size_t)(NCH - 1) * TL;
        for (int i = t; i < 1024; i += 256) {
            const int p = i >> 4, j = i & 15;
            float4 o = *(const float4*)(pbase + p * PST + 4 * j);
            *(float4*)(ob + (size_t)p * L_ + 4 * j) = o;
        }
    }
}

extern "C" void kernel_launch(void* const* d_in, const int* in_sizes, int n_in,
                              void* d_out, int out_size, void* d_ws, size_t ws_size,
                              hipStream_t stream) {
    const float* u    = (const float*)d_in[0];  // [B, H, L]
    const float* w_in = (const float*)d_in[1];  // [P, H]
    const float* w_hh = (const float*)d_in[2];  // [P, P] (diag used)
    const float* bias = (const float*)d_in[3];  // [P]
    float* out = (float*)d_out;                 // [B, P, L]

    dim3 grid(B_ * (P_ / PB));  // 512 blocks
    dim3 block(256);
    esn_fused<<<grid, block, 0, stream>>>(u, w_in, w_hh, bias, out);
}